// Round 8
// baseline (212.226 us; speedup 1.0000x reference)
//
#include <hip/hip_runtime.h>
#include <math.h>

#define II 2048
#define BB 256
#define JJ 10
#define ICH 16            // i's per block
#define IW 2              // i's per staged chunk
#define NCH (ICH/IW)      // 8
#define ICHUNKS (II/ICH)  // 128
#define BBLK 32           // b's per block (4 waves x 8)
#define NBW 8             // b's per wave
#define SJE (BB*JJ*16)    // 40960
#define WSLOT 320         // float4 slots per i (10j x 32)

typedef __attribute__((address_space(3))) unsigned lds_u32;
typedef __attribute__((address_space(1))) const unsigned glb_u32;
typedef float v2f __attribute__((ext_vector_type(2)));

__device__ __forceinline__ void gload16(const float* g, float* l) {
  __builtin_amdgcn_global_load_lds((glb_u32*)g, (lds_u32*)l, 16, 0, 0);
}
__device__ __forceinline__ v2f mkv2(float a, float b) { v2f r; r.x = a; r.y = b; return r; }

// DPP row (16-lane) rotate: VALU-pipe cross-lane, no LDS traffic.
template<int N>
__device__ __forceinline__ float rrot16(float v) {
  const int i = __float_as_int(v);
  return __int_as_float(__builtin_amdgcn_update_dpp(i, i, 0x120 + N, 0xF, 0xF, false));
}
__device__ __forceinline__ float rsum16(float v) {
  v += rrot16<8>(v); v += rrot16<4>(v); v += rrot16<2>(v); v += rrot16<1>(v);
  return v;
}
__device__ __forceinline__ float xor16swz(float v) {  // lane ^ 16 (within 32-halves)
  return __int_as_float(__builtin_amdgcn_ds_swizzle(__float_as_int(v), 0x401F));
}

// wave = 16 j-slots x 4 e-groups; each wave owns 8 b's, loops them per i.
// W swizzle: phys_f4slot = log ^ (j&7) within each 32-slot row (key = jr&7,
// pad map jr = j-8 keeps lane octets bank-uniform). x now staged PER CHUNK
// (dbuf, 4 KB) by waves 2-3 while waves 0-1 stage the W tail -> LDS total
// 24.6 KB (PASS0/1) / 36.1 KB (PASS2) for 6/4 resident blocks per CU.
// PASS2 stages c (fp16) in LDS, coalesced write at epilogue. Softmax skips
// max-subtraction (logits bounded; fp32 exp safe). Dots use packed f32 pairs.
template<int PASS, bool ATOMIC>
__global__ __launch_bounds__(256, 1)
void routing_pass(const float* __restrict__ x, const float* __restrict__ W,
                  const float* __restrict__ o_eff, float* __restrict__ sdst,
                  float* __restrict__ out) {
  __shared__ __align__(16) float w_lds[2 * 640 * 4];              // 20 KB (dbuf W)
  __shared__ __align__(16) float x_dbf[2 * 128 * 4];              // 4 KB (dbuf x)
  __shared__ _Float16 c_tile[(PASS == 2) ? (BBLK * JJ * 18) : 4]; // 11.25 KB (PASS2)

  const int t = threadIdx.x;
  const int wid = t >> 6;
  const int lane = t & 63;
  const int eg = lane >> 4;            // e-group 0..3 (e = eg*4+q)
  const int j = lane & 15;             // capsule slot, valid < 10
  const int jv = (j < JJ);
  const int jr = jv ? j : (j - 8);     // in-bounds, octet-bank-uniform
  const int key = jr & 7;
  const int b0 = blockIdx.y * BBLK;
  const int bw = __builtin_amdgcn_readfirstlane(b0 + wid * NBW);
  const int i0 = blockIdx.x * ICH;

  int woff[8];
#pragma unroll
  for (int r = 0; r < 8; ++r) woff[r] = (jr * 32 + eg * 8 + (r ^ key)) * 4;

  float4 o4[NBW];
  if (PASS > 0) {
    const int jo = jv ? j : 0;
#pragma unroll
    for (int nb = 0; nb < NBW; ++nb)
      o4[nb] = *reinterpret_cast<const float4*>(
          o_eff + ((size_t)(bw + nb) * JJ + jo) * 16 + eg * 4);
  }

  float4 acc4[NBW];
#pragma unroll
  for (int nb = 0; nb < NBW; ++nb) acc4[nb] = make_float4(0.f, 0.f, 0.f, 0.f);

  // stage W (640 f4 slots) + x (128 f4 slots) for one chunk.
  // r=0,1: all 4 waves -> W slots 0..511. r=2: waves 0-1 -> W slots 512..639,
  // waves 2-3 -> x slots 0..127 (slot = bl*4 + iw*2 + h).
  auto stage = [&](int ch, int buf) {
    const int ibase = i0 + ch * IW;
#pragma unroll
    for (int r = 0; r < 2; ++r) {
      const int p = r * 256 + t;                 // phys W slot
      const int iL = (p >= WSLOT) ? 1 : 0;
      const int pm = p - iL * WSLOT;
      const int jj = pm >> 5;
      const int wl = (pm & 31) ^ (jj & 7);       // logical float4 within row
      const float* src = W + ((size_t)jj * II + (ibase + iL)) * 128 + wl * 4;
      gload16(src, &w_lds[(buf * 640 + r * 256 + wid * 64) * 4]);
    }
    if (wid < 2) {
      const int p = 512 + t;                     // W slots 512..639
      const int iL = (p >= WSLOT) ? 1 : 0;
      const int pm = p - iL * WSLOT;
      const int jj = pm >> 5;
      const int wl = (pm & 31) ^ (jj & 7);
      const float* src = W + ((size_t)jj * II + (ibase + iL)) * 128 + wl * 4;
      gload16(src, &w_lds[(buf * 640 + 512 + wid * 64) * 4]);
    } else {
      const int s = (wid - 2) * 64 + lane;       // x slot 0..127
      const int bl = s >> 2, iw = (s >> 1) & 1, h = s & 1;
      const float* src = x + ((size_t)(b0 + bl) * II + (ibase + iw)) * 8 + h * 4;
      gload16(src, &x_dbf[(buf * 128 + (wid - 2) * 64) * 4]);
    }
  };

  auto compute_i = [&](int buf, int iw, int i) {
    const int cbase = (buf * 640 + iw * WSLOT) * 4;
    float4 wv[8];
#pragma unroll
    for (int r = 0; r < 8; ++r)
      wv[r] = *reinterpret_cast<const float4*>(&w_lds[cbase + woff[r]]);

    const int il = i - i0;
#pragma unroll
    for (int nb = 0; nb < NBW; ++nb) {
      // slot = bl*4 + iw*2 ; floats at slot*4 (wave-uniform -> broadcast)
      const float* xp = &x_dbf[(buf * 128 + (wid * NBW + nb) * 4 + iw * 2) * 4];
      const float4 xa = *reinterpret_cast<const float4*>(xp);
      const float4 xb = *reinterpret_cast<const float4*>(xp + 4);
      // packed-f32 dot8: d-pairs accumulate in v2f, horizontal add at end
#define DOT8(q, dst)                                                        \
      v2f dv##q = mkv2(wv[2*(q)].x, wv[2*(q)].y) * mkv2(xa.x, xa.y);        \
      dv##q = __builtin_elementwise_fma(mkv2(wv[2*(q)].z, wv[2*(q)].w),     \
                                        mkv2(xa.z, xa.w), dv##q);           \
      dv##q = __builtin_elementwise_fma(mkv2(wv[2*(q)+1].x, wv[2*(q)+1].y), \
                                        mkv2(xb.x, xb.y), dv##q);           \
      dv##q = __builtin_elementwise_fma(mkv2(wv[2*(q)+1].z, wv[2*(q)+1].w), \
                                        mkv2(xb.z, xb.w), dv##q);           \
      const float dst = dv##q.x + dv##q.y;
      DOT8(0, u0) DOT8(1, u1) DOT8(2, u2) DOT8(3, u3)
#undef DOT8
      float c;
      if (PASS == 0) {
        c = 0.1f;                                 // b-logits = 0 -> uniform over 10
      } else {
        float lp = o4[nb].x * u0;
        lp = fmaf(o4[nb].y, u1, lp);
        lp = fmaf(o4[nb].z, u2, lp);
        lp = fmaf(o4[nb].w, u3, lp);
        lp += xor16swz(lp);                       // reduce over 4 e-groups
        lp += __shfl_xor(lp, 32);
        // no max-subtraction: |logit| bounded (~20), fp32 exp safe
        const float pp = jv ? __expf(lp) : 0.f;
        const float su = rsum16(pp);              // DPP, VALU pipe
        c = pp * __builtin_amdgcn_rcpf(su);
      }
      acc4[nb].x = fmaf(c, u0, acc4[nb].x);
      acc4[nb].y = fmaf(c, u1, acc4[nb].y);
      acc4[nb].z = fmaf(c, u2, acc4[nb].z);
      acc4[nb].w = fmaf(c, u3, acc4[nb].w);
      if (PASS == 2) {
        if (eg == 0 && jv)
          c_tile[((wid * NBW + nb) * JJ + j) * 18 + il] = (_Float16)c;
      }
    }
  };

  stage(0, 0);
  __syncthreads();
  for (int ch = 0; ch < NCH; ++ch) {
    const int buf = ch & 1;
    if (ch + 1 < NCH) stage(ch + 1, buf ^ 1);
    compute_i(buf, 0, i0 + ch * IW);
    compute_i(buf, 1, i0 + ch * IW + 1);
    __syncthreads();
  }

  if (PASS == 2) {
    // coalesced c write: 320 rows x 16 i-floats (64 B contiguous per row)
    for (int s = t; s < BBLK * JJ * ICH; s += 256) {
      const int row = s >> 4, col = s & 15;
      const int bb = row / 10, jj = row - bb * 10;
      out[((size_t)(b0 + bb) * JJ + jj) * 2064 + 16 + i0 + col] =
          (float)c_tile[row * 18 + col];
    }
  }

  if (jv) {
#pragma unroll
    for (int nb = 0; nb < NBW; ++nb) {
      if (ATOMIC) {
        float* sp = sdst + ((size_t)(bw + nb) * JJ + j) * 16 + eg * 4;
        atomicAdd(&sp[0], acc4[nb].x);
        atomicAdd(&sp[1], acc4[nb].y);
        atomicAdd(&sp[2], acc4[nb].z);
        atomicAdd(&sp[3], acc4[nb].w);
      } else {
        float* sp = sdst + (size_t)blockIdx.x * SJE +
                    ((size_t)(bw + nb) * JJ + j) * 16 + eg * 4;
        *reinterpret_cast<float4*>(sp) = acc4[nb];
      }
    }
  }
}

// fused: reduce over 128 i-chunk partials + squash + output/o_eff update
__global__ __launch_bounds__(256)
void finish_pass(const float* __restrict__ part, float* __restrict__ o_eff,
                 float* __restrict__ out, int pass) {
  const int idx = blockIdx.x * 256 + threadIdx.x;   // < 40960; 16 lanes = one (b,j)
  float a = 0.f;
#pragma unroll 8
  for (int k = 0; k < ICHUNKS; ++k) a += part[(size_t)k * SJE + idx];
  const float s2 = rsum16(a * a);
  const float scale = s2 / ((1.f + s2) * sqrtf(s2 + 1e-7f));
  const float v = scale * a;
  if (pass == 0) o_eff[idx] = v;
  else if (pass == 1) o_eff[idx] += v;
  else out[(size_t)(idx >> 4) * 2064 + (idx & 15)] = v;
}

__global__ __launch_bounds__(256)
void squash_update(const float* __restrict__ s, float* __restrict__ o_eff,
                   float* __restrict__ out, int pass) {
  const int idx = blockIdx.x * blockDim.x + threadIdx.x;
  if (idx >= BB * JJ) return;
  const float* sp = s + (size_t)idx * 16;
  float v[16];
  float s2 = 0.f;
#pragma unroll
  for (int e = 0; e < 16; ++e) { v[e] = sp[e]; s2 = fmaf(v[e], v[e], s2); }
  const float scale = s2 / ((1.f + s2) * sqrtf(s2 + 1e-7f));
  if (pass == 0) {
    float* op = o_eff + (size_t)idx * 16;
#pragma unroll
    for (int e = 0; e < 16; ++e) op[e] = scale * v[e];
  } else if (pass == 1) {
    float* op = o_eff + (size_t)idx * 16;
#pragma unroll
    for (int e = 0; e < 16; ++e) op[e] += scale * v[e];
  } else {
    float* dst = out + (size_t)idx * 2064;
#pragma unroll
    for (int e = 0; e < 16; ++e) dst[e] = scale * v[e];
  }
}

extern "C" void kernel_launch(void* const* d_in, const int* in_sizes, int n_in,
                              void* d_out, int out_size, void* d_ws, size_t ws_size,
                              hipStream_t stream) {
  const float* x = (const float*)d_in[0];   // [256,2048,8]
  const float* W = (const float*)d_in[1];   // [10,2048,16,8]
  float* out = (float*)d_out;               // [256,10,2064]
  float* ws = (float*)d_ws;

  const dim3 grid(ICHUNKS, BB / BBLK);      // (128, 8) = 1024 blocks
  const size_t need = ((size_t)ICHUNKS * SJE + SJE) * sizeof(float); // ~21.1 MB

  if (ws_size >= need) {
    float* part = ws;
    float* oe   = ws + (size_t)ICHUNKS * SJE;
    routing_pass<0, false><<<grid, 256, 0, stream>>>(x, W, nullptr, part, nullptr);
    finish_pass<<<SJE / 256, 256, 0, stream>>>(part, oe, out, 0);
    routing_pass<1, false><<<grid, 256, 0, stream>>>(x, W, oe, part, nullptr);
    finish_pass<<<SJE / 256, 256, 0, stream>>>(part, oe, out, 1);
    routing_pass<2, false><<<grid, 256, 0, stream>>>(x, W, oe, part, out);
    finish_pass<<<SJE / 256, 256, 0, stream>>>(part, oe, out, 2);
  } else {
    float* s0 = ws;
    float* s1 = ws + SJE;
    float* s2 = ws + 2 * SJE;
    float* oe = ws + 3 * SJE;
    hipMemsetAsync(ws, 0, (size_t)4 * SJE * sizeof(float), stream);
    routing_pass<0, true><<<grid, 256, 0, stream>>>(x, W, nullptr, s0, nullptr);
    squash_update<<<10, 256, 0, stream>>>(s0, oe, out, 0);
    routing_pass<1, true><<<grid, 256, 0, stream>>>(x, W, oe, s1, nullptr);
    squash_update<<<10, 256, 0, stream>>>(s1, oe, out, 1);
    routing_pass<2, true><<<grid, 256, 0, stream>>>(x, W, oe, s2, out);
    squash_update<<<10, 256, 0, stream>>>(s2, oe, out, 2);
  }
}